// Round 4
// baseline (87.320 us; speedup 1.0000x reference)
//
#include <hip/hip_runtime.h>
#include <math.h>

#define N_PRED 12
#define B      256
#define N_NEG  128
#define D      512
#define LOG2E  1.4426950408889634f
#define LN2    0.6931471805599453f

__device__ __forceinline__ float ex2(float x) { return __builtin_amdgcn_exp2f(x); }

// One block per (t,b). 4 waves. Each wave processes 2 negs per iteration,
// 32 lanes per neg (g = lane>>5 picks the neg, q = lane&31 the d-slice).
// Cyclic d-mapping: lane q owns float4 indices q+32j (j=0..3) -> each load
// instruction covers 2 contiguous 512B segments (fully coalesced).
// 16 floats/lane of pred (16 VGPRs) keeps total VGPR <= 64 so we get
// 8 waves/SIMD (the 64-VGPR occupancy cliff bit round 3 at VGPR=72).
__global__ __launch_bounds__(256, 8) void fk_kernel(
    const float* __restrict__ lp,        // (13,256,512)
    const float* __restrict__ ps,        // (12,256,512)
    const int*   __restrict__ time_idx,  // (12,256,128)
    const int*   __restrict__ batch_idx, // (12,256,128)
    float* __restrict__ per_step,        // (12*256)
    float* __restrict__ flags)           // (12*256)
{
    const int tb   = blockIdx.x;   // 0..3071
    const int t    = tb >> 8;
    const int b    = tb & (B - 1);
    const int tid  = threadIdx.x;
    const int wave = tid >> 6;
    const int lane = tid & 63;
    const int q    = lane & 31;    // d-slice within neg-group
    const int g    = lane >> 5;    // neg-group id (0..1)

    __shared__ int   s_ti[N_NEG];
    __shared__ int   s_bi[N_NEG];
    __shared__ float s_sum[4];
    __shared__ int   s_ok[4];

    // Stage this block's 128 (ti,bi) index pairs into LDS once.
    const int idx_base = (t * B + b) * N_NEG;
    if (tid < N_NEG) s_ti[tid]         = time_idx[idx_base + tid];
    else             s_bi[tid - N_NEG] = batch_idx[idx_base + tid - N_NEG];

    // pred slice for this lane (cyclic), pre-scaled by log2(e).
    const float4* pred4 = (const float4*)(lp + ((size_t)(t + 1) * B + b) * D) + q;
    float4 p[4];
#pragma unroll
    for (int j = 0; j < 4; ++j) {
        float4 v = pred4[j * 32];
        v.x *= LOG2E; v.y *= LOG2E; v.z *= LOG2E; v.w *= LOG2E;
        p[j] = v;
    }

    // fk_pos (both 32-lane groups compute the identical value concurrently)
    const float4* pos4 = (const float4*)(ps + ((size_t)t * B + b) * D) + q;
    float a0 = 0.f, a1 = 0.f, a2 = 0.f, a3 = 0.f;
#pragma unroll
    for (int j = 0; j < 4; ++j) {
        float4 y = pos4[j * 32];
        a0 += ex2(p[j].x * y.x);
        a1 += ex2(p[j].y * y.y);
        a2 += ex2(p[j].z * y.z);
        a3 += ex2(p[j].w * y.w);
    }
    float s = (a0 + a1) + (a2 + a3);
#pragma unroll
    for (int off = 1; off < 32; off <<= 1) s += __shfl_xor(s, off, 64);
    const float fk_pos = s;   // uniform across the wave

    __syncthreads();          // indices staged

    float negsum = 0.0f;
    bool  all_ok = true;

    for (int it = 0; it < 16; ++it) {
        const int n  = wave * 32 + it * 2 + g;
        const int ti = s_ti[n];
        const int bi = s_bi[n];
        // bank[ti, bi, :] : ti==0 -> lp[0, bi], else ps[ti-1, bi]
        const float* row = (ti == 0) ? (lp + (size_t)bi * D)
                                     : (ps + ((size_t)(ti - 1) * B + bi) * D);
        const float4* row4 = (const float4*)row + q;
        float b0 = 0.f, b1 = 0.f, b2 = 0.f, b3 = 0.f;
#pragma unroll
        for (int j = 0; j < 4; ++j) {
            float4 y = row4[j * 32];
            b0 += ex2(p[j].x * y.x);
            b1 += ex2(p[j].y * y.y);
            b2 += ex2(p[j].z * y.z);
            b3 += ex2(p[j].w * y.w);
        }
        float fk = (b0 + b1) + (b2 + b3);
        // 5-step reduce within each 32-lane group (both groups concurrently)
#pragma unroll
        for (int off = 1; off < 32; off <<= 1) fk += __shfl_xor(fk, off, 64);
        negsum += fk;                  // identical in all 32 lanes of a group
        all_ok  = all_ok && (fk_pos > fk);
    }

    const int wave_ok = __all(all_ok ? 1 : 0);
    // Cross-group combine only (offset 32): exact wave total, 1 shuffle.
    float ns = negsum + __shfl_xor(negsum, 32, 64);

    if (lane == 0) { s_sum[wave] = ns; s_ok[wave] = wave_ok; }
    __syncthreads();
    if (tid == 0) {
        float total_neg = (s_sum[0] + s_sum[1]) + (s_sum[2] + s_sum[3]);
        int   ok        = s_ok[0] & s_ok[1] & s_ok[2] & s_ok[3];
        float total     = fk_pos + total_neg;
        float lg = (__builtin_amdgcn_logf(fk_pos) - __builtin_amdgcn_logf(total)) * LN2;
        per_step[tb] = lg;
        flags[tb]    = (float)ok;
    }
}

// Block 0: loss; blocks 1..12: correct_predictions[t]
__global__ __launch_bounds__(256) void reduce_kernel(
    const float* __restrict__ per_step,
    const float* __restrict__ flags,
    float* __restrict__ out)
{
    const int tid = threadIdx.x;
    const int j   = blockIdx.x;
    __shared__ float sh[4];

    float s = 0.0f;
    if (j == 0) {
#pragma unroll
        for (int t = 0; t < N_PRED; ++t) s += per_step[t * B + tid];
    } else {
        s = flags[(j - 1) * B + tid];
    }
#pragma unroll
    for (int off = 32; off > 0; off >>= 1) s += __shfl_xor(s, off, 64);
    if ((tid & 63) == 0) sh[tid >> 6] = s;
    __syncthreads();
    if (tid == 0) {
        float tot = (sh[0] + sh[1]) + (sh[2] + sh[3]);
        if (j == 0)
            out[0] = tot * (1.0f / ((float)(N_NEG + 1) * N_PRED * B));
        else
            out[j] = tot;
    }
}

extern "C" void kernel_launch(void* const* d_in, const int* in_sizes, int n_in,
                              void* d_out, int out_size, void* d_ws, size_t ws_size,
                              hipStream_t stream) {
    const float* lp        = (const float*)d_in[0];
    const float* ps        = (const float*)d_in[1];
    const int*   time_idx  = (const int*)d_in[2];
    const int*   batch_idx = (const int*)d_in[3];
    float* out = (float*)d_out;

    float* per_step = (float*)d_ws;
    float* flags    = per_step + N_PRED * B;

    fk_kernel<<<N_PRED * B, 256, 0, stream>>>(lp, ps, time_idx, batch_idx,
                                              per_step, flags);
    reduce_kernel<<<1 + N_PRED, 256, 0, stream>>>(per_step, flags, out);
}

// Round 5
// 57.654 us; speedup vs baseline: 1.5146x; 1.5146x over previous
//
#include <hip/hip_runtime.h>
#include <math.h>

#define N_PRED 12
#define B      256
#define N_NEG  128
#define D      512
#define LOG2E  1.4426950408889634f
#define LN2    0.6931471805599453f

typedef float f2 __attribute__((ext_vector_type(2)));

__device__ __forceinline__ float ex2(float x) { return __builtin_amdgcn_exp2f(x); }

// Sum over this lane's 32 d-elements (cyclic float4 q+16j) of exp2(p*y).
// Packed f32 muls/adds (v_pk_*_f32); exp2 scalar on the trans pipe.
__device__ __forceinline__ float row_partial(const float4* __restrict__ r4,
                                             const f2* __restrict__ p2) {
    f2 acc = {0.f, 0.f};
#pragma unroll
    for (int j = 0; j < 8; ++j) {
        float4 y = r4[j * 16];
        f2 m0 = p2[2 * j]     * f2{y.x, y.y};
        f2 m1 = p2[2 * j + 1] * f2{y.z, y.w};
        f2 e0, e1;
        e0.x = ex2(m0.x); e0.y = ex2(m0.y);
        e1.x = ex2(m1.x); e1.y = ex2(m1.y);
        acc += e0;
        acc += e1;
    }
    return acc.x + acc.y;
}

// One block per (t,b). 4 waves. Each wave: 4 negs/iter, 16 lanes/neg,
// cyclic d-mapping (lane q owns float4 indices q+16j) => every load
// instruction covers 4 contiguous 256B segments (fully coalesced).
// Per-neg row ADDRESSES precomputed once into LDS.
__global__ __launch_bounds__(256) void fk_kernel(
    const float* __restrict__ lp,        // (13,256,512)
    const float* __restrict__ ps,        // (12,256,512)
    const int*   __restrict__ time_idx,  // (12,256,128)
    const int*   __restrict__ batch_idx, // (12,256,128)
    float* __restrict__ per_step,        // (12*256)
    float* __restrict__ flags)           // (12*256)
{
    const int tb   = blockIdx.x;   // 0..3071
    const int t    = tb >> 8;
    const int b    = tb & (B - 1);
    const int tid  = threadIdx.x;
    const int wave = tid >> 6;
    const int lane = tid & 63;
    const int q    = lane & 15;    // d-slice within neg-group
    const int g    = lane >> 4;    // neg-group id (0..3)

    __shared__ const float* s_row[N_NEG];
    __shared__ float s_sum[4];
    __shared__ int   s_ok[4];

    // Stage per-neg row base addresses once (removes per-iter select+imul).
    const int idx_base = (t * B + b) * N_NEG;
    if (tid < N_NEG) {
        const int ti = time_idx[idx_base + tid];
        const int bi = batch_idx[idx_base + tid];
        s_row[tid] = (ti == 0) ? (lp + (size_t)bi * D)
                               : (ps + ((size_t)(ti - 1) * B + bi) * D);
    }

    // pred slice (cyclic), pre-scaled by log2(e), stored as 16 packed f2.
    const float4* pred4 = (const float4*)(lp + ((size_t)(t + 1) * B + b) * D) + q;
    f2 p2[16];
#pragma unroll
    for (int j = 0; j < 8; ++j) {
        float4 v = pred4[j * 16];
        p2[2 * j]     = f2{v.x * LOG2E, v.y * LOG2E};
        p2[2 * j + 1] = f2{v.z * LOG2E, v.w * LOG2E};
    }

    // fk_pos (all 4 groups compute the identical value concurrently)
    const float4* pos4 = (const float4*)(ps + ((size_t)t * B + b) * D) + q;
    float s = row_partial(pos4, p2);
#pragma unroll
    for (int off = 1; off < 16; off <<= 1) s += __shfl_xor(s, off, 64);
    const float fk_pos = s;   // uniform across the wave

    __syncthreads();          // addresses staged

    float negsum = 0.0f;
    bool  all_ok = true;

#pragma unroll 2
    for (int it = 0; it < 8; ++it) {
        const int n = wave * 32 + it * 4 + g;
        const float4* row4 = (const float4*)s_row[n] + q;
        float fk = row_partial(row4, p2);
        // 4-step reduce within each 16-lane group (all 4 groups concurrently)
#pragma unroll
        for (int off = 1; off < 16; off <<= 1) fk += __shfl_xor(fk, off, 64);
        negsum += fk;                  // identical in all 16 lanes of a group
        all_ok  = all_ok && (fk_pos > fk);
    }

    const int wave_ok = __all(all_ok ? 1 : 0);
    // Cross-group combine only (offsets 16,32): exact wave total, 2 shuffles.
    float ns = negsum;
#pragma unroll
    for (int off = 16; off < 64; off <<= 1) ns += __shfl_xor(ns, off, 64);

    if (lane == 0) { s_sum[wave] = ns; s_ok[wave] = wave_ok; }
    __syncthreads();
    if (tid == 0) {
        float total_neg = (s_sum[0] + s_sum[1]) + (s_sum[2] + s_sum[3]);
        int   ok        = s_ok[0] & s_ok[1] & s_ok[2] & s_ok[3];
        float total     = fk_pos + total_neg;
        float lg = (__builtin_amdgcn_logf(fk_pos) - __builtin_amdgcn_logf(total)) * LN2;
        per_step[tb] = lg;
        flags[tb]    = (float)ok;
    }
}

// Block 0: loss; blocks 1..12: correct_predictions[t]
__global__ __launch_bounds__(256) void reduce_kernel(
    const float* __restrict__ per_step,
    const float* __restrict__ flags,
    float* __restrict__ out)
{
    const int tid = threadIdx.x;
    const int j   = blockIdx.x;
    __shared__ float sh[4];

    float s = 0.0f;
    if (j == 0) {
#pragma unroll
        for (int t = 0; t < N_PRED; ++t) s += per_step[t * B + tid];
    } else {
        s = flags[(j - 1) * B + tid];
    }
#pragma unroll
    for (int off = 32; off > 0; off >>= 1) s += __shfl_xor(s, off, 64);
    if ((tid & 63) == 0) sh[tid >> 6] = s;
    __syncthreads();
    if (tid == 0) {
        float tot = (sh[0] + sh[1]) + (sh[2] + sh[3]);
        if (j == 0)
            out[0] = tot * (1.0f / ((float)(N_NEG + 1) * N_PRED * B));
        else
            out[j] = tot;
    }
}

extern "C" void kernel_launch(void* const* d_in, const int* in_sizes, int n_in,
                              void* d_out, int out_size, void* d_ws, size_t ws_size,
                              hipStream_t stream) {
    const float* lp        = (const float*)d_in[0];
    const float* ps        = (const float*)d_in[1];
    const int*   time_idx  = (const int*)d_in[2];
    const int*   batch_idx = (const int*)d_in[3];
    float* out = (float*)d_out;

    float* per_step = (float*)d_ws;
    float* flags    = per_step + N_PRED * B;

    fk_kernel<<<N_PRED * B, 256, 0, stream>>>(lp, ps, time_idx, batch_idx,
                                              per_step, flags);
    reduce_kernel<<<1 + N_PRED, 256, 0, stream>>>(per_step, flags, out);
}

// Round 6
// 55.974 us; speedup vs baseline: 1.5600x; 1.0300x over previous
//
#include <hip/hip_runtime.h>
#include <math.h>

#define N_PRED 12
#define B      256
#define N_NEG  128
#define D      512
#define LOG2E  1.4426950408889634f
#define LN2    0.6931471805599453f

typedef float f2 __attribute__((ext_vector_type(2)));

__device__ __forceinline__ float ex2(float x) { return __builtin_amdgcn_exp2f(x); }

// exp-sum over this lane's 32 d-elements from a preloaded register buffer.
__device__ __forceinline__ float buf_partial(const float4* __restrict__ y,
                                             const f2* __restrict__ p2) {
    f2 acc = {0.f, 0.f};
#pragma unroll
    for (int j = 0; j < 8; ++j) {
        f2 m0 = p2[2 * j]     * f2{y[j].x, y[j].y};
        f2 m1 = p2[2 * j + 1] * f2{y[j].z, y[j].w};
        f2 e0, e1;
        e0.x = ex2(m0.x); e0.y = ex2(m0.y);
        e1.x = ex2(m1.x); e1.y = ex2(m1.y);
        acc += e0;
        acc += e1;
    }
    return acc.x + acc.y;
}

__device__ __forceinline__ void load_row(float4* __restrict__ y,
                                         const float* __restrict__ row, int q) {
    const float4* r4 = (const float4*)row + q;
#pragma unroll
    for (int j = 0; j < 8; ++j) y[j] = r4[j * 16];
}

// One block per (t,b). 4 waves. Each wave: 4 negs per pipeline stage,
// 16 lanes/neg, cyclic d-mapping (lane q owns float4 indices q+16j) so each
// load instruction covers 4 contiguous 256B segments (fully coalesced).
// Explicit A/B software pipeline: while computing stage i, stage i+1's
// 8 float4 gather loads are already in flight -> load-use distance = one
// full exp/pk compute block (~300 cyc), hiding L2/L3 latency even at
// ~4 waves/SIMD.
__global__ __launch_bounds__(256) void fk_kernel(
    const float* __restrict__ lp,        // (13,256,512)
    const float* __restrict__ ps,        // (12,256,512)
    const int*   __restrict__ time_idx,  // (12,256,128)
    const int*   __restrict__ batch_idx, // (12,256,128)
    float* __restrict__ per_step,        // (12*256)
    float* __restrict__ flags)           // (12*256)
{
    const int tb   = blockIdx.x;   // 0..3071
    const int t    = tb >> 8;
    const int b    = tb & (B - 1);
    const int tid  = threadIdx.x;
    const int wave = tid >> 6;
    const int lane = tid & 63;
    const int q    = lane & 15;    // d-slice within neg-group
    const int g    = lane >> 4;    // neg-group id (0..3)

    __shared__ const float* s_row[N_NEG];
    __shared__ float s_sum[4];
    __shared__ int   s_ok[4];

    // Stage per-neg row base addresses once.
    const int idx_base = (t * B + b) * N_NEG;
    if (tid < N_NEG) {
        const int ti = time_idx[idx_base + tid];
        const int bi = batch_idx[idx_base + tid];
        s_row[tid] = (ti == 0) ? (lp + (size_t)bi * D)
                               : (ps + ((size_t)(ti - 1) * B + bi) * D);
    }

    // pred slice (cyclic), pre-scaled by log2(e), as 16 packed f2.
    const float4* pred4 = (const float4*)(lp + ((size_t)(t + 1) * B + b) * D) + q;
    f2 p2[16];
#pragma unroll
    for (int j = 0; j < 8; ++j) {
        float4 v = pred4[j * 16];
        p2[2 * j]     = f2{v.x * LOG2E, v.y * LOG2E};
        p2[2 * j + 1] = f2{v.z * LOG2E, v.w * LOG2E};
    }

    // fk_pos (all 4 groups compute the identical value concurrently)
    float fk_pos;
    {
        const float4* pos4 = (const float4*)(ps + ((size_t)t * B + b) * D) + q;
        float4 ypos[8];
#pragma unroll
        for (int j = 0; j < 8; ++j) ypos[j] = pos4[j * 16];
        float s = buf_partial(ypos, p2);
#pragma unroll
        for (int off = 1; off < 16; off <<= 1) s += __shfl_xor(s, off, 64);
        fk_pos = s;           // uniform across the wave
    }

    __syncthreads();          // addresses staged

    float negsum = 0.0f;
    bool  all_ok = true;

    float4 ya[8], yb[8];
    load_row(ya, s_row[wave * 32 + g], q);           // stage 0

#pragma unroll 1
    for (int it = 0; it < 8; it += 2) {
        // issue stage it+1 loads (always valid: it+1 <= 7)
        load_row(yb, s_row[wave * 32 + (it + 1) * 4 + g], q);

        // compute stage it from ya
        {
            float fk = buf_partial(ya, p2);
#pragma unroll
            for (int off = 1; off < 16; off <<= 1) fk += __shfl_xor(fk, off, 64);
            negsum += fk;
            all_ok  = all_ok && (fk_pos > fk);
        }

        // issue stage it+2 loads
        if (it + 2 < 8)
            load_row(ya, s_row[wave * 32 + (it + 2) * 4 + g], q);

        // compute stage it+1 from yb
        {
            float fk = buf_partial(yb, p2);
#pragma unroll
            for (int off = 1; off < 16; off <<= 1) fk += __shfl_xor(fk, off, 64);
            negsum += fk;
            all_ok  = all_ok && (fk_pos > fk);
        }
    }

    const int wave_ok = __all(all_ok ? 1 : 0);
    // Cross-group combine only (offsets 16,32): exact wave total, 2 shuffles.
    float ns = negsum;
#pragma unroll
    for (int off = 16; off < 64; off <<= 1) ns += __shfl_xor(ns, off, 64);

    if (lane == 0) { s_sum[wave] = ns; s_ok[wave] = wave_ok; }
    __syncthreads();
    if (tid == 0) {
        float total_neg = (s_sum[0] + s_sum[1]) + (s_sum[2] + s_sum[3]);
        int   ok        = s_ok[0] & s_ok[1] & s_ok[2] & s_ok[3];
        float total     = fk_pos + total_neg;
        float lg = (__builtin_amdgcn_logf(fk_pos) - __builtin_amdgcn_logf(total)) * LN2;
        per_step[tb] = lg;
        flags[tb]    = (float)ok;
    }
}

// Block 0: loss; blocks 1..12: correct_predictions[t]
__global__ __launch_bounds__(256) void reduce_kernel(
    const float* __restrict__ per_step,
    const float* __restrict__ flags,
    float* __restrict__ out)
{
    const int tid = threadIdx.x;
    const int j   = blockIdx.x;
    __shared__ float sh[4];

    float s = 0.0f;
    if (j == 0) {
#pragma unroll
        for (int t = 0; t < N_PRED; ++t) s += per_step[t * B + tid];
    } else {
        s = flags[(j - 1) * B + tid];
    }
#pragma unroll
    for (int off = 32; off > 0; off >>= 1) s += __shfl_xor(s, off, 64);
    if ((tid & 63) == 0) sh[tid >> 6] = s;
    __syncthreads();
    if (tid == 0) {
        float tot = (sh[0] + sh[1]) + (sh[2] + sh[3]);
        if (j == 0)
            out[0] = tot * (1.0f / ((float)(N_NEG + 1) * N_PRED * B));
        else
            out[j] = tot;
    }
}

extern "C" void kernel_launch(void* const* d_in, const int* in_sizes, int n_in,
                              void* d_out, int out_size, void* d_ws, size_t ws_size,
                              hipStream_t stream) {
    const float* lp        = (const float*)d_in[0];
    const float* ps        = (const float*)d_in[1];
    const int*   time_idx  = (const int*)d_in[2];
    const int*   batch_idx = (const int*)d_in[3];
    float* out = (float*)d_out;

    float* per_step = (float*)d_ws;
    float* flags    = per_step + N_PRED * B;

    fk_kernel<<<N_PRED * B, 256, 0, stream>>>(lp, ps, time_idx, batch_idx,
                                              per_step, flags);
    reduce_kernel<<<1 + N_PRED, 256, 0, stream>>>(per_step, flags, out);
}